// Round 2
// baseline (465.598 us; speedup 1.0000x reference)
//
#include <hip/hip_runtime.h>
#include <math.h>

// Problem constants (from reference)
#define NN 50000   // nodes
#define RR 32      // relations
#define HH 16      // hidden
#define CC 8       // classes

// ---------------- kernels ----------------

// cnt[d*R + r] += 1 per edge  (layout [d][r] so each dst's inv row is L1-local)
__global__ void count_k(const int* __restrict__ et, const int* __restrict__ dst,
                        float* __restrict__ cnt, int E) {
    int stride = gridDim.x * blockDim.x;
    for (int i = blockIdx.x * blockDim.x + threadIdx.x; i < E; i += stride)
        atomicAdd(&cnt[dst[i] * RR + et[i]], 1.0f);
}

// per-d: deg[d] = sum_r cnt[d][r];  cnt[d][r] -> 1/max(cnt,1)
// 32 lanes per d (aligned), butterfly reduce
__global__ void invdeg_k(float* __restrict__ cnt, int* __restrict__ deg) {
    int gid = blockIdx.x * blockDim.x + threadIdx.x;
    int d = gid >> 5;
    int j = gid & 31;
    if (d >= NN) return;
    float c = cnt[d * RR + j];
    float s = c;
#pragma unroll
    for (int m = 1; m < 32; m <<= 1) s += __shfl_xor(s, m);
    if (j == 0) deg[d] = (int)s;
    cnt[d * RR + j] = 1.0f / fmaxf(c, 1.0f);
}

// single-block exclusive scan of deg[NN] -> off[NN+1], cur[NN]
__global__ void scan_k(const int* __restrict__ deg, int* __restrict__ off,
                       int* __restrict__ cur) {
    __shared__ int lds[1024];
    int t = threadIdx.x;
    const int chunk = (NN + 1023) / 1024;  // 49
    int beg = t * chunk;
    int end = beg + chunk; if (end > NN) end = NN;
    int s = 0;
    for (int i = beg; i < end; ++i) s += deg[i];
    lds[t] = s;
    __syncthreads();
    for (int ofs = 1; ofs < 1024; ofs <<= 1) {
        int add = (t >= ofs) ? lds[t - ofs] : 0;
        __syncthreads();
        lds[t] += add;
        __syncthreads();
    }
    int run = lds[t] - s;  // exclusive prefix for this chunk
    for (int i = beg; i < end; ++i) {
        off[i] = run; cur[i] = run;
        run += deg[i];
    }
    if (t == 1023) off[NN] = lds[1023];
}

// bucket[pos] = (r<<16)|s per edge, pos from per-dst cursor
__global__ void scatter_k(const int* __restrict__ src, const int* __restrict__ dst,
                          const int* __restrict__ et, int* __restrict__ cur,
                          unsigned int* __restrict__ bucket, int E) {
    int stride = gridDim.x * blockDim.x;
    for (int i = blockIdx.x * blockDim.x + threadIdx.x; i < E; i += stride) {
        int d = dst[i];
        int pos = atomicAdd(&cur[d], 1);
        bucket[pos] = ((unsigned)et[i] << 16) | (unsigned)src[i];
    }
}

// layer 1 gather: one wave per dst; 4 edge-subgroups x 16 channels.
// h[d,:] = relu( sum_e inv[d,r_e]*w1[r_e,s_e,:] + root1[d,:] + bias1 )
__global__ void layer1g_k(const unsigned int* __restrict__ bucket,
                          const int* __restrict__ off, const float* __restrict__ inv,
                          const float* __restrict__ w1, const float* __restrict__ root1,
                          const float* __restrict__ bias1, float* __restrict__ h) {
    int gid = blockIdx.x * blockDim.x + threadIdx.x;
    int d = gid >> 6;
    if (d >= NN) return;
    int lane = threadIdx.x & 63;
    int sub = lane >> 4, ch = lane & 15;
    int b0 = off[d], b1 = off[d + 1];
    float acc = 0.f;
    for (int i = b0 + sub; i < b1; i += 4) {
        unsigned e = bucket[i];
        int r = e >> 16, s = e & 0xFFFF;
        float sc = inv[d * RR + r];
        acc += w1[(r * NN + s) * HH + ch] * sc;
    }
    acc += __shfl_xor(acc, 16);
    acc += __shfl_xor(acc, 32);
    if (lane < HH) {
        float v = acc + root1[d * HH + lane] + bias1[lane];
        h[d * HH + lane] = fmaxf(v, 0.f);
    }
}

// layer 2 gather + epilogue: one wave per dst; 8 edge-subgroups x 8 classes.
// out[d,:] = log_softmax( sum_e inv*w2[r]^T h[s] + root2^T h[d] + bias2 )
__global__ void layer2g_k(const unsigned int* __restrict__ bucket,
                          const int* __restrict__ off, const float* __restrict__ inv,
                          const float* __restrict__ h, const float* __restrict__ w2,
                          const float* __restrict__ root2, const float* __restrict__ bias2,
                          float* __restrict__ out) {
    int gid = blockIdx.x * blockDim.x + threadIdx.x;
    int d = gid >> 6;
    if (d >= NN) return;
    int lane = threadIdx.x & 63;
    int sub = lane >> 3, c = lane & 7;
    int b0 = off[d], b1 = off[d + 1];
    float acc = 0.f;
    for (int i = b0 + sub; i < b1; i += 8) {
        unsigned e = bucket[i];
        int r = e >> 16, s = e & 0xFFFF;
        float sc = inv[d * RR + r];
        const float* hs = h + s * HH;
        const float* wr = w2 + r * HH * CC;
        float t = 0.f;
#pragma unroll
        for (int f = 0; f < HH; ++f) t += hs[f] * wr[f * CC + c];
        acc += t * sc;
    }
    acc += __shfl_xor(acc, 8);
    acc += __shfl_xor(acc, 16);
    acc += __shfl_xor(acc, 32);
    // root path + bias (redundant across subgroups, cheap)
    float v = bias2[c];
    const float* hd = h + d * HH;
#pragma unroll
    for (int f = 0; f < HH; ++f) v += hd[f] * root2[f * CC + c];
    v += acc;
    // log_softmax across the 8 class lanes
    float m = v;
#pragma unroll
    for (int msk = 1; msk < 8; msk <<= 1) m = fmaxf(m, __shfl_xor(m, msk));
    float ex = expf(v - m);
    float ssum = ex;
#pragma unroll
    for (int msk = 1; msk < 8; msk <<= 1) ssum += __shfl_xor(ssum, msk);
    float res = v - m - logf(ssum);
    if (lane < CC) out[d * CC + lane] = res;
}

// ---------------- launch ----------------

extern "C" void kernel_launch(void* const* d_in, const int* in_sizes, int n_in,
                              void* d_out, int out_size, void* d_ws, size_t ws_size,
                              hipStream_t stream) {
    const int*   edge_index = (const int*)d_in[0];   // (2, E)
    const int*   edge_type  = (const int*)d_in[1];   // (E,)
    const float* weight1    = (const float*)d_in[2]; // (R, N, H)
    const float* root1      = (const float*)d_in[3]; // (N, H)
    const float* bias1      = (const float*)d_in[4]; // (H,)
    const float* weight2    = (const float*)d_in[5]; // (R, H, C)
    const float* root2      = (const float*)d_in[6]; // (H, C)
    const float* bias2      = (const float*)d_in[7]; // (C,)
    float* out = (float*)d_out;

    const int E = in_sizes[1];
    const int* src = edge_index;
    const int* dst = edge_index + E;

    // workspace layout
    char* ws = (char*)d_ws;
    float* cnt = (float*)ws;            ws += sizeof(float) * (size_t)NN * RR;  // 6.4 MB
    int* deg   = (int*)ws;              ws += sizeof(int) * NN;
    int* off   = (int*)ws;              ws += sizeof(int) * (NN + 1);
    int* cur   = (int*)ws;              ws += sizeof(int) * NN;
    unsigned int* bucket = (unsigned int*)ws;  ws += sizeof(unsigned int) * (size_t)E; // 6.4 MB
    float* h   = (float*)ws;            ws += sizeof(float) * (size_t)NN * HH;  // 3.2 MB

    hipMemsetAsync(cnt, 0, sizeof(float) * (size_t)NN * RR, stream);

    const int B = 256;
    int g_e = min((E + B - 1) / B, 2048);

    count_k<<<g_e, B, 0, stream>>>(edge_type, dst, cnt, E);
    invdeg_k<<<(NN * 32 + B - 1) / B, B, 0, stream>>>(cnt, deg);
    scan_k<<<1, 1024, 0, stream>>>(deg, off, cur);
    scatter_k<<<g_e, B, 0, stream>>>(src, dst, edge_type, cur, bucket, E);

    int g_d = (NN * 64 + B - 1) / B;  // one wave per dst
    layer1g_k<<<g_d, B, 0, stream>>>(bucket, off, cnt, weight1, root1, bias1, h);
    layer2g_k<<<g_d, B, 0, stream>>>(bucket, off, cnt, h, weight2, root2, bias2, out);
}

// Round 3
// 409.001 us; speedup vs baseline: 1.1384x; 1.1384x over previous
//
#include <hip/hip_runtime.h>
#include <math.h>

#define NN 50000
#define RR 32
#define HH 16
#define CC 8
#define SHIFT 7
#define BSZ (1 << SHIFT)                    // 128 dsts per bucket
#define NB ((NN + BSZ - 1) >> SHIFT)        // 391 buckets
#define G 256                               // hist/scatter blocks
#define W2S 132                             // padded LDS stride for w2 rows

// ---------------- phase 0: per-(d,r) counts -> inv ----------------

__global__ void count_k(const int* __restrict__ et, const int* __restrict__ dst,
                        float* __restrict__ cnt, int E) {
    int i = blockIdx.x * blockDim.x + threadIdx.x;
    if (i < E) atomicAdd(&cnt[dst[i] * RR + et[i]], 1.0f);
}

__global__ void inv_k(float* __restrict__ cnt, int n) {
    int i = blockIdx.x * blockDim.x + threadIdx.x;
    if (i < n) cnt[i] = 1.0f / fmaxf(cnt[i], 1.0f);
}

// ---------------- phase 1: bucket edges by dst>>SHIFT (counting sort) ----------------

__global__ void hist_k(const int* __restrict__ dst, int* __restrict__ hist, int E) {
    __shared__ int lh[NB];
    int g = blockIdx.x, tid = threadIdx.x;
    for (int j = tid; j < NB; j += 256) lh[j] = 0;
    __syncthreads();
    int chunk = (E + G - 1) / G;
    int beg = g * chunk, end = min(beg + chunk, E);
    for (int i = beg + tid; i < end; i += 256)
        atomicAdd(&lh[dst[i] >> SHIFT], 1);
    __syncthreads();
    for (int j = tid; j < NB; j += 256) hist[g * NB + j] = lh[j];
}

__global__ void scan2_k(const int* __restrict__ hist, int* __restrict__ pos,
                        int* __restrict__ boff, int E) {
    __shared__ int lds[1024];
    int b = threadIdx.x;
    int total = 0;
    if (b < NB)
        for (int g = 0; g < G; ++g) total += hist[g * NB + b];
    lds[b] = (b < NB) ? total : 0;
    __syncthreads();
    for (int ofs = 1; ofs < 1024; ofs <<= 1) {
        int add = (b >= ofs) ? lds[b - ofs] : 0;
        __syncthreads();
        lds[b] += add;
        __syncthreads();
    }
    if (b < NB) {
        int base = lds[b] - total;   // exclusive prefix over buckets
        boff[b] = base;
        int run = base;
        for (int g = 0; g < G; ++g) { pos[g * NB + b] = run; run += hist[g * NB + b]; }
    }
    if (b == 0) boff[NB] = E;
}

__global__ void scatter2_k(const int* __restrict__ src, const int* __restrict__ dst,
                           const int* __restrict__ et, const int* __restrict__ pos,
                           unsigned* __restrict__ bucket, int E) {
    __shared__ int cur[NB];
    int g = blockIdx.x, tid = threadIdx.x;
    for (int j = tid; j < NB; j += 256) cur[j] = pos[g * NB + j];
    __syncthreads();
    int chunk = (E + G - 1) / G;
    int beg = g * chunk, end = min(beg + chunk, E);
    for (int i = beg + tid; i < end; i += 256) {
        int d = dst[i];
        int bk = d >> SHIFT;
        int p = atomicAdd(&cur[bk], 1);
        bucket[p] = (unsigned)src[i] | ((unsigned)et[i] << 16) |
                    ((unsigned)(d & (BSZ - 1)) << 21);
    }
}

// ---------------- layer 1: per-bucket LDS-privatized gather ----------------
// h[d,:] = relu( sum_e inv[d,r_e]*w1[r_e,s_e,:] + root1[d,:] + bias1 )

__global__ __launch_bounds__(512) void layer1_k(
        const unsigned* __restrict__ bucket, const int* __restrict__ boff,
        const float* __restrict__ inv, const float4* __restrict__ w1v,
        const float* __restrict__ root1, const float* __restrict__ bias1,
        float* __restrict__ h) {
    __shared__ float tile[BSZ * HH];  // 8 KB
    int b = blockIdx.x, tid = threadIdx.x;
    for (int j = tid; j < BSZ * HH; j += 512) tile[j] = 0.f;
    __syncthreads();
    int e0 = boff[b], n = boff[b + 1] - e0;
    int d0 = b << SHIFT;
    int ndst = NN - d0; if (ndst > BSZ) ndst = BSZ;
    for (int i = tid; i < n * 4; i += 512) {
        unsigned rec = bucket[e0 + (i >> 2)];
        int q  = i & 3;
        int s  = rec & 0xFFFF;
        int r  = (rec >> 16) & 31;
        int dl = rec >> 21;
        float sc = inv[(d0 + dl) * RR + r];
        float4 w = w1v[(r * NN + s) * (HH / 4) + q];
        float* t = &tile[dl * HH + q * 4];
        atomicAdd(t + 0, w.x * sc); atomicAdd(t + 1, w.y * sc);
        atomicAdd(t + 2, w.z * sc); atomicAdd(t + 3, w.w * sc);
    }
    __syncthreads();
    for (int j = tid; j < ndst * HH; j += 512) {
        int dl = j >> 4, ch = j & 15;
        int d = d0 + dl;
        float v = tile[dl * HH + ch] + root1[d * HH + ch] + bias1[ch];
        h[d * HH + ch] = fmaxf(v, 0.f);
    }
}

// ---------------- layer 2: per-bucket gather + fused epilogue ----------------
// out[d,:] = log_softmax( sum_e inv*(w2[r]^T h[s]) + root2^T h[d] + bias2 )

__global__ __launch_bounds__(512) void layer2_k(
        const unsigned* __restrict__ bucket, const int* __restrict__ boff,
        const float* __restrict__ inv, const float* __restrict__ h,
        const float* __restrict__ w2, const float* __restrict__ root2,
        const float* __restrict__ bias2, float* __restrict__ out) {
    __shared__ float otile[BSZ * CC];   // 4 KB
    __shared__ float w2p[RR * W2S];     // 16.9 KB, bank-spread stride
    int b = blockIdx.x, tid = threadIdx.x;
    for (int j = tid; j < BSZ * CC; j += 512) otile[j] = 0.f;
    for (int j = tid; j < RR * HH * CC; j += 512) {
        int r = j >> 7, fc = j & 127;
        w2p[r * W2S + fc] = w2[j];
    }
    __syncthreads();
    int e0 = boff[b], n = boff[b + 1] - e0;
    int d0 = b << SHIFT;
    int ndst = NN - d0; if (ndst > BSZ) ndst = BSZ;
    for (int i = tid; i < n * 2; i += 512) {
        unsigned rec = bucket[e0 + (i >> 1)];
        int c0 = (i & 1) * 4;
        int s  = rec & 0xFFFF;
        int r  = (rec >> 16) & 31;
        int dl = rec >> 21;
        float sc = inv[(d0 + dl) * RR + r];
        const float4* hv = (const float4*)(h + s * HH);
        float4 h0 = hv[0], h1 = hv[1], h2 = hv[2], h3 = hv[3];
        float hr[16] = {h0.x, h0.y, h0.z, h0.w, h1.x, h1.y, h1.z, h1.w,
                        h2.x, h2.y, h2.z, h2.w, h3.x, h3.y, h3.z, h3.w};
        float ax = 0.f, ay = 0.f, az = 0.f, aw = 0.f;
        const float* wbase = &w2p[r * W2S + c0];
#pragma unroll
        for (int f = 0; f < HH; ++f) {
            float4 wv = *(const float4*)(wbase + f * CC);
            ax += hr[f] * wv.x; ay += hr[f] * wv.y;
            az += hr[f] * wv.z; aw += hr[f] * wv.w;
        }
        float* t = &otile[dl * CC + c0];
        atomicAdd(t + 0, ax * sc); atomicAdd(t + 1, ay * sc);
        atomicAdd(t + 2, az * sc); atomicAdd(t + 3, aw * sc);
    }
    __syncthreads();
    // epilogue: one thread per dst
    for (int dl = tid; dl < ndst; dl += 512) {
        int d = d0 + dl;
        const float4* hv = (const float4*)(h + d * HH);
        float4 h0 = hv[0], h1 = hv[1], h2 = hv[2], h3 = hv[3];
        float hr[16] = {h0.x, h0.y, h0.z, h0.w, h1.x, h1.y, h1.z, h1.w,
                        h2.x, h2.y, h2.z, h2.w, h3.x, h3.y, h3.z, h3.w};
        float v[CC];
#pragma unroll
        for (int c = 0; c < CC; ++c) {
            float a = otile[dl * CC + c] + bias2[c];
#pragma unroll
            for (int f = 0; f < HH; ++f) a += hr[f] * root2[f * CC + c];
            v[c] = a;
        }
        float m = v[0];
#pragma unroll
        for (int c = 1; c < CC; ++c) m = fmaxf(m, v[c]);
        float ssum = 0.f;
#pragma unroll
        for (int c = 0; c < CC; ++c) ssum += expf(v[c] - m);
        float l = logf(ssum);
#pragma unroll
        for (int c = 0; c < CC; ++c) out[d * CC + c] = v[c] - m - l;
    }
}

// ---------------- launch ----------------

extern "C" void kernel_launch(void* const* d_in, const int* in_sizes, int n_in,
                              void* d_out, int out_size, void* d_ws, size_t ws_size,
                              hipStream_t stream) {
    const int*   edge_index = (const int*)d_in[0];   // (2, E)
    const int*   edge_type  = (const int*)d_in[1];   // (E,)
    const float* weight1    = (const float*)d_in[2]; // (R, N, H)
    const float* root1      = (const float*)d_in[3]; // (N, H)
    const float* bias1      = (const float*)d_in[4]; // (H,)
    const float* weight2    = (const float*)d_in[5]; // (R, H, C)
    const float* root2      = (const float*)d_in[6]; // (H, C)
    const float* bias2      = (const float*)d_in[7]; // (C,)
    float* out = (float*)d_out;

    const int E = in_sizes[1];
    const int* src = edge_index;
    const int* dst = edge_index + E;

    // workspace layout
    char* ws = (char*)d_ws;
    float* cnt = (float*)ws;          ws += sizeof(float) * (size_t)NN * RR;      // 6.4 MB
    int* hist  = (int*)ws;            ws += sizeof(int) * (size_t)G * NB;         // 0.4 MB
    int* pos   = (int*)ws;            ws += sizeof(int) * (size_t)G * NB;         // 0.4 MB
    int* boff  = (int*)ws;            ws += sizeof(int) * (NB + 1);
    unsigned* bucket = (unsigned*)ws; ws += sizeof(unsigned) * (size_t)E;         // 6.4 MB
    float* h   = (float*)ws;          ws += sizeof(float) * (size_t)NN * HH;      // 3.2 MB

    hipMemsetAsync(cnt, 0, sizeof(float) * (size_t)NN * RR, stream);

    const int B = 256;
    count_k<<<(E + B - 1) / B, B, 0, stream>>>(edge_type, dst, cnt, E);
    inv_k<<<(NN * RR + B - 1) / B, B, 0, stream>>>(cnt, NN * RR);

    hist_k<<<G, B, 0, stream>>>(dst, hist, E);
    scan2_k<<<1, 1024, 0, stream>>>(hist, pos, boff, E);
    scatter2_k<<<G, B, 0, stream>>>(src, dst, edge_type, pos, bucket, E);

    layer1_k<<<NB, 512, 0, stream>>>(bucket, boff, cnt, (const float4*)weight1,
                                     root1, bias1, h);
    layer2_k<<<NB, 512, 0, stream>>>(bucket, boff, cnt, h, weight2, root2, bias2, out);
}